// Round 4
// baseline (128.483 us; speedup 1.0000x reference)
//
#include <hip/hip_runtime.h>

// IDWT2D db4, periodized. Input x: [64][256][256][16] f32 (cA|cH|cV|cD x 4ch),
// output: [64][512][512][4] f32.
//
// R3: separable two-pass, chunked 2 j-rows/iter, single 32 KB LDS buffer.
// Pass1 (y-filter): thread=(col,lohi-half), 4-row register sliding window,
// writes I[jr][p][lohi][col]. Pass2 (x-filter): thread=(jx, jrow-sel),
// computes BOTH column parities q (16 ds_read_b128 -> 4 output float4;
// 3 of every 4 reads use immediate LDS offsets). 1 sync per j-row.

#define N 256
#define RJ 8

__device__ __forceinline__ void fma4(float4& d, float s, const float4 a) {
  d.x = fmaf(s, a.x, d.x);
  d.y = fmaf(s, a.y, d.y);
  d.z = fmaf(s, a.z, d.z);
  d.w = fmaf(s, a.w, d.w);
}

__global__ __launch_bounds__(512, 4) void idwt2_sep3_kernel(
    const float* __restrict__ x, float* __restrict__ out) {
  constexpr float LO[8] = {
      0.23037781330885523f,  0.7148465705525415f,  0.6308807679295904f,
      -0.02798376941698385f, -0.18703481171888114f, 0.030841381835986965f,
      0.032883011666982945f, -0.010597401784997278f};
  constexpr float HIW[8] = {
      -0.010597401784997278f, -0.032883011666982945f, 0.030841381835986965f,
      0.18703481171888114f,  -0.02798376941698385f,  -0.6308807679295904f,
      0.7148465705525415f,   -0.23037781330885523f};
  const float Lw[2][4] = {{LO[6], LO[4], LO[2], LO[0]},
                          {LO[7], LO[5], LO[3], LO[1]}};
  const float Hw[2][4] = {{HIW[6], HIW[4], HIW[2], HIW[0]},
                          {HIW[7], HIW[5], HIW[3], HIW[1]}};

  __shared__ float4 I[2][2][2][N];  // [jr-slot][p][lo/hi][col], 32 KB

  const int t = threadIdx.x;
  const int rg = blockIdx.x & 31;
  const int b = blockIdx.x >> 5;
  const int r0 = rg * RJ;

  const float4* xb = reinterpret_cast<const float4*>(x) + (size_t)b * N * N * 4;
  float4* ob = reinterpret_cast<float4*>(out) + (size_t)b * (2 * N) * (2 * N);

  // ---- Pass1 identity: column + lo/hi half ----
  const int tcol = t & (N - 1);
  const int thalf = t >> 8;  // 0: lo from (cA,cH); 1: hi from (cV,cD)
  const float4* xcolp = xb + (size_t)tcol * 4 + thalf * 2;

  // 4-row register window (rows mod 4) + 2-row prefetch.
  float4 wA[4], wB[4];
#pragma unroll
  for (int m = 0; m < 4; ++m) {
    const int gr = (r0 + m) & (N - 1);
    wA[m] = xcolp[(size_t)gr * (N * 4)];
    wB[m] = xcolp[(size_t)gr * (N * 4) + 1];
  }
  float4 nA0, nB0, nA1, nB1;
  {
    int gr = (r0 + 4) & (N - 1);
    nA0 = xcolp[(size_t)gr * (N * 4)];
    nB0 = xcolp[(size_t)gr * (N * 4) + 1];
    gr = (r0 + 5) & (N - 1);
    nA1 = xcolp[(size_t)gr * (N * 4)];
    nB1 = xcolp[(size_t)gr * (N * 4) + 1];
  }

  // y-filter local j-row j into LDS slot jr.
  auto p1 = [&](int j, int jr) {
    float4 v0 = make_float4(0.f, 0.f, 0.f, 0.f);
    float4 v1 = make_float4(0.f, 0.f, 0.f, 0.f);
#pragma unroll
    for (int sy = 0; sy < 4; ++sy) {
      const float4 a = wA[(j + sy) & 3];
      const float4 bb = wB[(j + sy) & 3];
      fma4(v0, Lw[0][sy], a);
      fma4(v0, Hw[0][sy], bb);
      fma4(v1, Lw[1][sy], a);
      fma4(v1, Hw[1][sy], bb);
    }
    I[jr][0][thalf][tcol] = v0;
    I[jr][1][thalf][tcol] = v1;
  };

  // ---- Pass2 identity: jx + j-row select (wave-uniform) ----
  const int jx = t & (N - 1);
  const int jrsel = t >> 8;

#pragma unroll
  for (int k = 0; k < RJ / 2; ++k) {
    // ---- Pass1: two j-rows into slots 0,1 ----
    p1(2 * k + 0, 0);
    wA[(2 * k) & 3] = nA0;
    wB[(2 * k) & 3] = nB0;
    p1(2 * k + 1, 1);
    if (k < RJ / 2 - 1) {
      wA[(2 * k + 1) & 3] = nA1;
      wB[(2 * k + 1) & 3] = nB1;
    }
    __syncthreads();

    // ---- Prefetch next window rows (consumed next chunk's pass1) ----
    if (k < RJ / 2 - 1) {
      int gr = (r0 + 2 * k + 6) & (N - 1);
      nA0 = xcolp[(size_t)gr * (N * 4)];
      nB0 = xcolp[(size_t)gr * (N * 4) + 1];
      if (k < RJ / 2 - 2) {
        gr = (r0 + 2 * k + 7) & (N - 1);
        nA1 = xcolp[(size_t)gr * (N * 4)];
        nB1 = xcolp[(size_t)gr * (N * 4) + 1];
      }
    }

    // ---- Pass2: x-filter j-row (2k + jrsel), both q ----
    float4 o00 = make_float4(0.f, 0.f, 0.f, 0.f);
    float4 o01 = make_float4(0.f, 0.f, 0.f, 0.f);
    float4 o10 = make_float4(0.f, 0.f, 0.f, 0.f);
    float4 o11 = make_float4(0.f, 0.f, 0.f, 0.f);
#pragma unroll
    for (int s = 0; s < 4; ++s) {
      const int xc = (jx + s) & (N - 1);
      const float4 l0 = I[jrsel][0][0][xc];
      const float4 h0 = I[jrsel][0][1][xc];
      const float4 l1 = I[jrsel][1][0][xc];
      const float4 h1 = I[jrsel][1][1][xc];
      const float L0 = Lw[0][s], L1 = Lw[1][s];
      const float H0 = Hw[0][s], H1 = Hw[1][s];
      fma4(o00, L0, l0);
      fma4(o00, H0, h0);
      fma4(o01, L1, l0);
      fma4(o01, H1, h0);
      fma4(o10, L0, l1);
      fma4(o10, H0, h1);
      fma4(o11, L1, l1);
      fma4(o11, H1, h1);
    }
    const int jy = r0 + 2 * k + jrsel;
    const size_t base = (size_t)(2 * jy) * (2 * N) + 2 * jx;
    ob[base] = o00;
    ob[base + 1] = o01;
    ob[base + 2 * N] = o10;
    ob[base + 2 * N + 1] = o11;

    if (k < RJ / 2 - 1) __syncthreads();
  }
}

extern "C" void kernel_launch(void* const* d_in, const int* in_sizes, int n_in,
                              void* d_out, int out_size, void* d_ws,
                              size_t ws_size, hipStream_t stream) {
  const float* x = reinterpret_cast<const float*>(d_in[0]);
  float* out = reinterpret_cast<float*>(d_out);
  const int grid = 64 * (N / RJ);  // 2048 blocks
  idwt2_sep3_kernel<<<grid, 512, 0, stream>>>(x, out);
}